// Round 2
// baseline (11999.239 us; speedup 1.0000x reference)
//
#include <hip/hip_runtime.h>
#include <hip/hip_bf16.h>
#include <cstdint>
#include <cstddef>

#define T_LEN 4096
#define BATCH 32
#define NMELS 80
#define HID 128
#define W_WORDS 64
#define D_MAX 100
// halo layout for the 2D stage: (W_WORDS+4) x (D_MAX+4)
#define DH 104
#define WH 68
#define PLANE (WH * DH) // 7072

// ---------------- transpose w4/w5: w[co][ci][tap] -> wt[ci][tap][co] ----------------
__global__ __launch_bounds__(256) void transpose_w_kernel(const float* __restrict__ w,
                                                          float* __restrict__ wt) {
    int idx = blockIdx.x * 256 + threadIdx.x; // 128*25*128 = 409600
    if (idx >= 128 * 25 * 128) return;
    int co = idx & 127;
    int r = idx >> 7;
    int tap = r % 25;
    int ci = r / 25;
    wt[idx] = w[(co * 128 + ci) * 25 + tap];
}

// ---------------- conv1d: in (C,CIN,T) * w (128,CIN,5) -> out (C,128,T), SAME ----------------
template <int CIN, bool RELU>
__global__ __launch_bounds__(256) void conv1d_kernel(const float* __restrict__ in,
                                                     const float* __restrict__ w,
                                                     const float* __restrict__ bias,
                                                     float* __restrict__ out) {
    __shared__ float wl[CIN * 5 * 8]; // [ci][k][co8]
    const int tid = threadIdx.x;
    const int co_base = blockIdx.y * 8;
    const int b = blockIdx.z;

    for (int i = tid; i < CIN * 40; i += 256) {
        int co = i & 7;
        int r = i >> 3;
        int k = r % 5;
        int ci = r / 5;
        wl[(ci * 5 + k) * 8 + co] = w[((co_base + co) * CIN + ci) * 5 + k];
    }
    __syncthreads();

    const int warp = tid >> 6, lane = tid & 63;
    const int t0 = blockIdx.x * 1024 + warp * 256 + lane; // + 64*j, j=0..3
    const float* inb = in + (size_t)b * CIN * T_LEN;

    float acc[4][8];
#pragma unroll
    for (int j = 0; j < 4; j++)
#pragma unroll
        for (int q = 0; q < 8; q++) acc[j][q] = 0.f;

#pragma unroll 1
    for (int ci = 0; ci < CIN; ci++) {
        const float* row = inb + (size_t)ci * T_LEN;
#pragma unroll
        for (int k = 0; k < 5; k++) {
            const float4 wa = *(const float4*)&wl[(ci * 5 + k) * 8];
            const float4 wb = *(const float4*)&wl[(ci * 5 + k) * 8 + 4];
#pragma unroll
            for (int j = 0; j < 4; j++) {
                int idx = t0 + 64 * j + k - 2;
                float xv = 0.f;
                if ((unsigned)idx < (unsigned)T_LEN) xv = row[idx];
                acc[j][0] += xv * wa.x;
                acc[j][1] += xv * wa.y;
                acc[j][2] += xv * wa.z;
                acc[j][3] += xv * wa.w;
                acc[j][4] += xv * wb.x;
                acc[j][5] += xv * wb.y;
                acc[j][6] += xv * wb.z;
                acc[j][7] += xv * wb.w;
            }
        }
    }

    float bv[8];
#pragma unroll
    for (int q = 0; q < 8; q++) bv[q] = bias[co_base + q];

#pragma unroll
    for (int j = 0; j < 4; j++) {
#pragma unroll
        for (int q = 0; q < 8; q++) {
            float v = acc[j][q] + bv[q];
            if (RELU) v = fmaxf(v, 0.f);
            out[((size_t)b * HID + co_base + q) * T_LEN + t0 + 64 * j] = v;
        }
    }
}

// ---------------- gather words: emb (C,128,T) -> P (C,128,WH,DH) interior (full overwrite) ----------------
__global__ __launch_bounds__(256) void gather_kernel(const float* __restrict__ emb,
                                                     const int* __restrict__ wb,
                                                     float* __restrict__ P) {
    const int w = blockIdx.x; // 64
    const int b = blockIdx.y; // chunk-local
    const int start = wb[(b * W_WORDS + w) * 2 + 0];
    const int end = wb[(b * W_WORDS + w) * 2 + 1];
    const int dur = end - start;
    float* Pb = P + (size_t)b * HID * PLANE + (w + 2) * DH + 2;
    const float* eb = emb + (size_t)b * HID * T_LEN + start;
    for (int i = threadIdx.x; i < HID * D_MAX; i += 256) {
        int c = i / 100;
        int d = i - c * 100;
        float v = (d < dur) ? eb[(size_t)c * T_LEN + d] : 0.f;
        Pb[(size_t)c * PLANE + d] = v;
    }
}

// ---------------- conv2d 5x5 SAME: in (C,128,WH,DH halo) -> out (C,128,WH,DH interior) ----------------
// wt layout: [ci][tap][co] (128,25,128)
template <bool RELU>
__global__ __launch_bounds__(256) void conv2d_kernel(const float* __restrict__ in,
                                                     const float* __restrict__ wt,
                                                     const float* __restrict__ bias,
                                                     float* __restrict__ out) {
    const int tid = threadIdx.x;
    const int warp = tid >> 6, lane = tid & 63;
    const int co_base = blockIdx.y * 64 + warp * 16;
    const int b = blockIdx.z;
    const int p0 = blockIdx.x * 256 + lane; // + 64*pj

    int poff[4], pooff[4];
#pragma unroll
    for (int pj = 0; pj < 4; pj++) {
        int p = p0 + 64 * pj; // < 6400
        int wp = p / 100;
        int dp = p - wp * 100;
        poff[pj] = wp * DH + dp;            // input base (tap (0,0) == w-2,d-2 in halo coords)
        pooff[pj] = (wp + 2) * DH + dp + 2; // output interior
    }

    const float* inb = in + (size_t)b * HID * PLANE;

    float acc[4][16];
#pragma unroll
    for (int pj = 0; pj < 4; pj++)
#pragma unroll
        for (int q = 0; q < 16; q++) acc[pj][q] = 0.f;

#pragma unroll 1
    for (int ci = 0; ci < 128; ci++) {
        const float* pv0 = inb + (size_t)ci * PLANE + poff[0];
        const float* pv1 = inb + (size_t)ci * PLANE + poff[1];
        const float* pv2 = inb + (size_t)ci * PLANE + poff[2];
        const float* pv3 = inb + (size_t)ci * PLANE + poff[3];
        const float* wrow = wt + (size_t)ci * 25 * 128 + co_base;
#pragma unroll
        for (int kh = 0; kh < 5; kh++) {
#pragma unroll
            for (int kw = 0; kw < 5; kw++) {
                const int tap = kh * 5 + kw;
                const float4 w0 = *(const float4*)&wrow[tap * 128 + 0];
                const float4 w1 = *(const float4*)&wrow[tap * 128 + 4];
                const float4 w2 = *(const float4*)&wrow[tap * 128 + 8];
                const float4 w3 = *(const float4*)&wrow[tap * 128 + 12];
                const int off = kh * DH + kw;
                float v[4];
                v[0] = pv0[off];
                v[1] = pv1[off];
                v[2] = pv2[off];
                v[3] = pv3[off];
#pragma unroll
                for (int pj = 0; pj < 4; pj++) {
                    acc[pj][0] += v[pj] * w0.x;
                    acc[pj][1] += v[pj] * w0.y;
                    acc[pj][2] += v[pj] * w0.z;
                    acc[pj][3] += v[pj] * w0.w;
                    acc[pj][4] += v[pj] * w1.x;
                    acc[pj][5] += v[pj] * w1.y;
                    acc[pj][6] += v[pj] * w1.z;
                    acc[pj][7] += v[pj] * w1.w;
                    acc[pj][8] += v[pj] * w2.x;
                    acc[pj][9] += v[pj] * w2.y;
                    acc[pj][10] += v[pj] * w2.z;
                    acc[pj][11] += v[pj] * w2.w;
                    acc[pj][12] += v[pj] * w3.x;
                    acc[pj][13] += v[pj] * w3.y;
                    acc[pj][14] += v[pj] * w3.z;
                    acc[pj][15] += v[pj] * w3.w;
                }
            }
        }
    }

    float bv[16];
#pragma unroll
    for (int q = 0; q < 16; q++) bv[q] = bias[co_base + q];

#pragma unroll
    for (int pj = 0; pj < 4; pj++) {
#pragma unroll
        for (int q = 0; q < 16; q++) {
            float v = acc[pj][q] + bv[q];
            if (RELU) v = fmaxf(v, 0.f);
            out[((size_t)b * HID + co_base + q) * PLANE + pooff[pj]] = v;
        }
    }
}

// ---------------- einsum over d (len 100) + relu: x5 (halo layout, C batches) -> xe (C,128,64) ----------------
__global__ __launch_bounds__(256) void einsum_kernel(const float* __restrict__ x5,
                                                     const float* __restrict__ lw,
                                                     const float* __restrict__ lb,
                                                     float* __restrict__ xe) {
    int idx = blockIdx.x * 256 + threadIdx.x; // C*128*64
    int b = idx >> 13;
    int c = (idx >> 6) & 127;
    int w = idx & 63;
    const float* row = x5 + ((size_t)b * HID + c) * PLANE + (w + 2) * DH + 2;
    float acc = 0.f;
#pragma unroll 4
    for (int d = 0; d < 100; d++) acc += row[d] * lw[d];
    float v = acc + lb[0];
    xe[idx] = fmaxf(v, 0.f);
}

// ---------------- final conv: xe (B,128,64) -> out (B,64); only kw==2 column of w6 ----------------
__global__ void conv6_kernel(const float* __restrict__ xe, const float* __restrict__ w6,
                             const float* __restrict__ b6, float* __restrict__ out) {
    int b = blockIdx.x;
    int w = threadIdx.x; // 64
    float acc = b6[0];
#pragma unroll 1
    for (int ci = 0; ci < 128; ci++) {
        const float* xr = xe + (b * HID + ci) * 64;
#pragma unroll
        for (int kh = 0; kh < 5; kh++) {
            int ww = w + kh - 2;
            if ((unsigned)ww < 64u) acc += xr[ww] * w6[ci * 25 + kh * 5 + 2];
        }
    }
    out[b * 64 + w] = acc;
}

extern "C" void kernel_launch(void* const* d_in, const int* in_sizes, int n_in,
                              void* d_out, int out_size, void* d_ws, size_t ws_size,
                              hipStream_t stream) {
    const float* features = (const float*)d_in[0];
    const int* wbnd = (const int*)d_in[1];
    const float* w1 = (const float*)d_in[2];
    const float* b1 = (const float*)d_in[3];
    const float* w2 = (const float*)d_in[4];
    const float* b2 = (const float*)d_in[5];
    const float* w3 = (const float*)d_in[6];
    const float* b3 = (const float*)d_in[7];
    const float* w4 = (const float*)d_in[8];
    const float* b4 = (const float*)d_in[9];
    const float* w5 = (const float*)d_in[10];
    const float* b5 = (const float*)d_in[11];
    const float* lw = (const float*)d_in[12];
    const float* lb = (const float*)d_in[13];
    const float* w6 = (const float*)d_in[14];
    const float* b6 = (const float*)d_in[15];
    float* out = (float*)d_out;

    // choose batch chunk C (divisor of 32) to fit ws_size
    const size_t fixed_f = 2 * (size_t)128 * 25 * 128 + (size_t)BATCH * HID * W_WORDS;
    const size_t per_b_f = (size_t)HID * (2 * T_LEN + 2 * PLANE);
    int C = 32;
    while (C > 1 && (fixed_f + (size_t)C * per_b_f) * sizeof(float) > ws_size) C >>= 1;

    float* ws = (float*)d_ws;
    size_t off = 0;
    float* WT4 = ws + off; off += (size_t)128 * 25 * 128;
    float* WT5 = ws + off; off += (size_t)128 * 25 * 128;
    float* E   = ws + off; off += (size_t)BATCH * HID * W_WORDS; // xe, full batch
    float* A   = ws + off; off += (size_t)C * HID * T_LEN;       // h1 / emb (chunk)
    float* Bf  = ws + off; off += (size_t)C * HID * T_LEN;       // h2 (chunk)
    float* P   = ws + off; off += (size_t)C * HID * PLANE;       // padded / x5 (chunk)
    float* X   = ws + off; off += (size_t)C * HID * PLANE;       // x4 (chunk)

    // zero halo planes once per call (gather fully overwrites interior; conv2d writes all interior)
    hipMemsetAsync(P, 0, (size_t)C * HID * PLANE * sizeof(float), stream);
    hipMemsetAsync(X, 0, (size_t)C * HID * PLANE * sizeof(float), stream);

    transpose_w_kernel<<<1600, 256, 0, stream>>>(w4, WT4);
    transpose_w_kernel<<<1600, 256, 0, stream>>>(w5, WT5);

    for (int b0 = 0; b0 < BATCH; b0 += C) {
        const float* feat_c = features + (size_t)b0 * NMELS * T_LEN;
        const int* wb_c = wbnd + (size_t)b0 * W_WORDS * 2;
        float* E_c = E + (size_t)b0 * HID * W_WORDS;

        conv1d_kernel<NMELS, true><<<dim3(4, 16, C), 256, 0, stream>>>(feat_c, w1, b1, A);
        conv1d_kernel<HID, true><<<dim3(4, 16, C), 256, 0, stream>>>(A, w2, b2, Bf);
        conv1d_kernel<HID, false><<<dim3(4, 16, C), 256, 0, stream>>>(Bf, w3, b3, A);

        gather_kernel<<<dim3(64, C), 256, 0, stream>>>(A, wb_c, P);

        conv2d_kernel<true><<<dim3(25, 2, C), 256, 0, stream>>>(P, WT4, b4, X);
        conv2d_kernel<true><<<dim3(25, 2, C), 256, 0, stream>>>(X, WT5, b5, P);

        einsum_kernel<<<(unsigned)(C * HID * W_WORDS / 256), 256, 0, stream>>>(P, lw, lb, E_c);
    }

    conv6_kernel<<<32, 64, 0, stream>>>(E, w6, b6, out);
}

// Round 3
// 1002.993 us; speedup vs baseline: 11.9634x; 11.9634x over previous
//
#include <hip/hip_runtime.h>
#include <hip/hip_bf16.h>
#include <cstdint>
#include <cstddef>

#define T_LEN 4096
#define TP 4104      // padded t rows: pixel t lives at row t+2; rows 0,1 and 4098..4103 are zero
#define BATCH 32
#define NMELS 80
#define HID 128
#define W_WORDS 64
#define D_MAX 100
#define WHALO 68
#define DHALO 120    // pixel d at halo row d+2; rows 0,1 and 102..119 zero

typedef __attribute__((ext_vector_type(4))) float f32x4;
typedef __attribute__((ext_vector_type(8))) short short8;

static __device__ __forceinline__ unsigned short f2bf(float f) {
    __hip_bfloat16 h = __float2bfloat16(f);
    return *reinterpret_cast<unsigned short*>(&h);
}

// ---------- pack weights into MFMA A-fragment order ----------
// wf[((cc*TAPS + tap)*8 + mi)*512 + lane*8 + j] = w[co][ci][tap], co=mi*16+(lane&15), ci=cc*32+(lane>>4)*8+j
template <int CIN, int CC, int TAPS>
__global__ __launch_bounds__(256) void pack_w_kernel(const float* __restrict__ w,
                                                     __hip_bfloat16* __restrict__ wf) {
    int idx = blockIdx.x * 256 + threadIdx.x; // CC*TAPS*8*64*8
    int r = idx;
    int j = r & 7; r >>= 3;
    int lane = r & 63; r >>= 6;
    int mi = r & 7; r >>= 3;
    int tap = r % TAPS;
    int cc = r / TAPS;
    if (cc >= CC) return;
    int co = mi * 16 + (lane & 15);
    int ci = cc * 32 + (lane >> 4) * 8 + j;
    float v = (ci < CIN) ? w[(co * CIN + ci) * TAPS + tap] : 0.f;
    wf[idx] = __float2bfloat16(v);
}

// ---------- cast features (b,80,t) fp32 -> XF (b,TP,96) bf16, interior rows ----------
__global__ __launch_bounds__(256) void cast_feat_kernel(const float* __restrict__ f,
                                                        __hip_bfloat16* __restrict__ xf) {
    int idx = blockIdx.x * 256 + threadIdx.x; // 32*4096*96
    int c = idx % 96;
    int r = idx / 96;
    int t = r & 4095;
    int b = r >> 12;
    float v = (c < NMELS) ? f[((size_t)b * NMELS + c) * T_LEN + t] : 0.f;
    xf[((size_t)b * TP + t + 2) * 96 + c] = __float2bfloat16(v);
}

// ---------- unified MFMA conv kernel ----------
// Computes out[pixel][co] = act( sum_{tap,ci} W[co][ci][tap] * In[pixel_shift(tap)][ci] + bias[co] )
// A-operand = packed weights (M=co), B-operand = activations (N=pixels, 16 per n-tile).
// OMODE: 0 = 1D (rows TP, out stride 128, +2 halo), 1 = 2D->halo plane, 2 = 2D->compact (b,64,100,128)
template <int IC, int CC, int TH, int TW, int PRS, int NT, bool RELU, bool DMASK, int OMODE, int D0>
__global__ __launch_bounds__(256) void convmfma_kernel(const __hip_bfloat16* __restrict__ in,
                                                       const __hip_bfloat16* __restrict__ wf,
                                                       const float* __restrict__ bias,
                                                       __hip_bfloat16* __restrict__ outp) {
    const int tid = threadIdx.x;
    const int lane = tid & 63;
    const int wid = tid >> 6;
    const int bx = blockIdx.x;
    const int b = blockIdx.y;

    int in_base, out_base;
    if (OMODE == 0) {
        const int pix0 = bx * 256 + wid * 64;
        in_base = (b * TP + pix0) * IC;
        out_base = (b * TP + pix0 + 2) * 128;
    } else {
        const int w = bx * 4 + wid;
        in_base = ((b * WHALO + w) * DHALO + D0) * IC;
        if (OMODE == 1)
            out_base = ((b * WHALO + w + 2) * DHALO + D0 + 2) * 128;
        else
            out_base = ((b * 64 + w) * 100 + D0) * 128;
    }

    f32x4 acc[NT][8];
#pragma unroll
    for (int n = 0; n < NT; n++)
#pragma unroll
        for (int mi = 0; mi < 8; mi++) acc[n][mi] = (f32x4)0.f;

    const short* inp = (const short*)in;
    const short* wfp = (const short*)wf;

#pragma unroll 1
    for (int cc = 0; cc < CC; cc++) {
#pragma unroll 1
        for (int th = 0; th < TH; th++) {
#pragma unroll
            for (int tw = 0; tw < TW; tw++) {
                const int tap = th * TW + tw;
                const short* wptr = wfp + ((cc * (TH * TW) + tap) * 8) * 512 + lane * 8;
                short8 wfr[8];
#pragma unroll
                for (int mi = 0; mi < 8; mi++) wfr[mi] = *(const short8*)(wptr + mi * 512);

                const short* xptr = inp + in_base + (th * PRS + tw) * IC + (lane & 15) * IC +
                                    (lane >> 4) * 8 + cc * 32;
                short8 xfr[NT];
#pragma unroll
                for (int n = 0; n < NT; n++) xfr[n] = *(const short8*)(xptr + n * 16 * IC);

#pragma unroll
                for (int n = 0; n < NT; n++)
#pragma unroll
                    for (int mi = 0; mi < 8; mi++)
                        acc[n][mi] = __builtin_amdgcn_mfma_f32_16x16x32_bf16(wfr[mi], xfr[n],
                                                                             acc[n][mi], 0, 0, 0);
            }
        }
    }

    unsigned short* outp16 = (unsigned short*)outp;
#pragma unroll
    for (int mi = 0; mi < 8; mi++) {
        const float4 bv = *(const float4*)(bias + mi * 16 + (lane >> 4) * 4);
#pragma unroll
        for (int n = 0; n < NT; n++) {
            const int pix = n * 16 + (lane & 15);
            if (DMASK && (D0 + pix >= 100)) continue;
            f32x4 v = acc[n][mi];
            float v0 = v[0] + bv.x, v1 = v[1] + bv.y, v2 = v[2] + bv.z, v3 = v[3] + bv.w;
            if (RELU) {
                v0 = fmaxf(v0, 0.f); v1 = fmaxf(v1, 0.f);
                v2 = fmaxf(v2, 0.f); v3 = fmaxf(v3, 0.f);
            }
            ushort4 o;
            o.x = f2bf(v0); o.y = f2bf(v1); o.z = f2bf(v2); o.w = f2bf(v3);
            *(ushort4*)(outp16 + out_base + pix * 128 + mi * 16 + (lane >> 4) * 4) = o;
        }
    }
}

// ---------- gather: E (b,TP,128) bf16 -> P4 (b,WHALO,DHALO,128) bf16 interior ----------
__global__ __launch_bounds__(256) void gather_kernel(const __hip_bfloat16* __restrict__ E,
                                                     const int* __restrict__ wb,
                                                     __hip_bfloat16* __restrict__ P) {
    const int w = blockIdx.x;
    const int b = blockIdx.y;
    const int start = wb[(b * W_WORDS + w) * 2 + 0];
    const int end = wb[(b * W_WORDS + w) * 2 + 1];
    const int dur = end - start;
    const int base_e = (b * TP + start + 2) * 128;
    const int base_p = ((b * WHALO + w + 2) * DHALO + 2) * 128;
    const unsigned short* ep = (const unsigned short*)E;
    unsigned short* pp = (unsigned short*)P;
    for (int i = threadIdx.x; i < D_MAX * 64; i += 256) {
        int c2 = (i & 63) * 2;
        int d = i >> 6;
        unsigned int v = (d < dur) ? *(const unsigned int*)(ep + base_e + d * 128 + c2) : 0u;
        *(unsigned int*)(pp + base_p + d * 128 + c2) = v;
    }
}

// ---------- einsum over d + relu: Q (b,64,100,128) bf16 -> xe (b,128,64) fp32 ----------
__global__ __launch_bounds__(128) void einsum_kernel(const __hip_bfloat16* __restrict__ Q,
                                                     const float* __restrict__ lw,
                                                     const float* __restrict__ lb,
                                                     float* __restrict__ xe) {
    const int w = blockIdx.x;
    const int b = blockIdx.y;
    const int c = threadIdx.x;
    const unsigned short* qp = (const unsigned short*)Q + ((b * 64 + w) * 100) * 128 + c;
    float acc = 0.f;
#pragma unroll 4
    for (int d = 0; d < D_MAX; d++) {
        unsigned int u = (unsigned int)qp[d * 128] << 16;
        acc += *reinterpret_cast<float*>(&u) * lw[d];
    }
    xe[(b * 128 + c) * 64 + w] = fmaxf(acc + lb[0], 0.f);
}

// ---------- final conv: xe (b,128,64) fp32 -> out (b,64); only kw==2 column of w6 ----------
__global__ void conv6_kernel(const float* __restrict__ xe, const float* __restrict__ w6,
                             const float* __restrict__ b6, float* __restrict__ out) {
    int b = blockIdx.x;
    int w = threadIdx.x; // 64
    float acc = b6[0];
#pragma unroll 1
    for (int ci = 0; ci < 128; ci++) {
        const float* xr = xe + (b * 128 + ci) * 64;
#pragma unroll
        for (int kh = 0; kh < 5; kh++) {
            int ww = w + kh - 2;
            if ((unsigned)ww < 64u) acc += xr[ww] * w6[ci * 25 + kh * 5 + 2];
        }
    }
    out[b * 64 + w] = acc;
}

extern "C" void kernel_launch(void* const* d_in, const int* in_sizes, int n_in,
                              void* d_out, int out_size, void* d_ws, size_t ws_size,
                              hipStream_t stream) {
    const float* features = (const float*)d_in[0];
    const int* wbnd = (const int*)d_in[1];
    const float* w1 = (const float*)d_in[2];
    const float* b1 = (const float*)d_in[3];
    const float* w2 = (const float*)d_in[4];
    const float* b2 = (const float*)d_in[5];
    const float* w3 = (const float*)d_in[6];
    const float* b3 = (const float*)d_in[7];
    const float* w4 = (const float*)d_in[8];
    const float* b4 = (const float*)d_in[9];
    const float* w5 = (const float*)d_in[10];
    const float* b5 = (const float*)d_in[11];
    const float* lw = (const float*)d_in[12];
    const float* lb = (const float*)d_in[13];
    const float* w6 = (const float*)d_in[14];
    const float* b6 = (const float*)d_in[15];
    float* out = (float*)d_out;

    char* base = (char*)d_ws;
    size_t off = 0;
    auto alloc = [&](size_t bytes) -> char* {
        char* p = base + off;
        off += (bytes + 255) & ~(size_t)255;
        return p;
    };

    __hip_bfloat16* XF = (__hip_bfloat16*)alloc((size_t)BATCH * TP * 96 * 2);
    __hip_bfloat16* Y1 = (__hip_bfloat16*)alloc((size_t)BATCH * TP * 128 * 2);
    __hip_bfloat16* Y2 = (__hip_bfloat16*)alloc((size_t)BATCH * TP * 128 * 2);
    __hip_bfloat16* P4 = (__hip_bfloat16*)alloc((size_t)BATCH * WHALO * DHALO * 128 * 2);
    __hip_bfloat16* P5 = (__hip_bfloat16*)alloc((size_t)BATCH * WHALO * DHALO * 128 * 2);
    float* XE = (float*)alloc((size_t)BATCH * 128 * 64 * 4);
    __hip_bfloat16* WF1 = (__hip_bfloat16*)alloc((size_t)3 * 5 * 8 * 512 * 2);
    __hip_bfloat16* WF2 = (__hip_bfloat16*)alloc((size_t)4 * 5 * 8 * 512 * 2);
    __hip_bfloat16* WF3 = (__hip_bfloat16*)alloc((size_t)4 * 5 * 8 * 512 * 2);
    __hip_bfloat16* WF4 = (__hip_bfloat16*)alloc((size_t)4 * 25 * 8 * 512 * 2);
    __hip_bfloat16* WF5 = (__hip_bfloat16*)alloc((size_t)4 * 25 * 8 * 512 * 2);
    __hip_bfloat16* Q = P4; // conv5 output reuses P4 (dead after conv4)

    // zero halos (and padding channels) — interiors are fully overwritten each call
    hipMemsetAsync(XF, 0, (size_t)BATCH * TP * 96 * 2, stream);
    hipMemsetAsync(Y1, 0, (size_t)BATCH * TP * 128 * 2, stream);
    hipMemsetAsync(Y2, 0, (size_t)BATCH * TP * 128 * 2, stream);
    hipMemsetAsync(P4, 0, (size_t)BATCH * WHALO * DHALO * 128 * 2, stream);
    hipMemsetAsync(P5, 0, (size_t)BATCH * WHALO * DHALO * 128 * 2, stream);

    pack_w_kernel<80, 3, 5><<<240, 256, 0, stream>>>(w1, WF1);
    pack_w_kernel<128, 4, 5><<<320, 256, 0, stream>>>(w2, WF2);
    pack_w_kernel<128, 4, 5><<<320, 256, 0, stream>>>(w3, WF3);
    pack_w_kernel<128, 4, 25><<<1600, 256, 0, stream>>>(w4, WF4);
    pack_w_kernel<128, 4, 25><<<1600, 256, 0, stream>>>(w5, WF5);

    cast_feat_kernel<<<49152, 256, 0, stream>>>(features, XF);

    // conv1d stack (1D: TH=5, TW=1, PRS=1, NT=4 -> 64 pixels/wave, 256/block)
    convmfma_kernel<96, 3, 5, 1, 1, 4, true, false, 0, 0>
        <<<dim3(16, 32), 256, 0, stream>>>(XF, WF1, b1, Y1);
    convmfma_kernel<128, 4, 5, 1, 1, 4, true, false, 0, 0>
        <<<dim3(16, 32), 256, 0, stream>>>(Y1, WF2, b2, Y2);
    convmfma_kernel<128, 4, 5, 1, 1, 4, false, false, 0, 0>
        <<<dim3(16, 32), 256, 0, stream>>>(Y2, WF3, b3, Y1); // E := Y1

    gather_kernel<<<dim3(64, 32), 256, 0, stream>>>(Y1, wbnd, P4);

    // conv4: P4 -> P5 (halo layout). main d 0..63, tail d 64..99 (masked)
    convmfma_kernel<128, 4, 5, 5, DHALO, 4, true, false, 1, 0>
        <<<dim3(16, 32), 256, 0, stream>>>(P4, WF4, b4, P5);
    convmfma_kernel<128, 4, 5, 5, DHALO, 3, true, true, 1, 64>
        <<<dim3(16, 32), 256, 0, stream>>>(P4, WF4, b4, P5);

    // conv5: P5 -> Q (compact b,64,100,128)
    convmfma_kernel<128, 4, 5, 5, DHALO, 4, true, false, 2, 0>
        <<<dim3(16, 32), 256, 0, stream>>>(P5, WF5, b5, Q);
    convmfma_kernel<128, 4, 5, 5, DHALO, 3, true, true, 2, 64>
        <<<dim3(16, 32), 256, 0, stream>>>(P5, WF5, b5, Q);

    einsum_kernel<<<dim3(64, 32), 128, 0, stream>>>(Q, lw, lb, XE);
    conv6_kernel<<<32, 64, 0, stream>>>(XE, w6, b6, out);
}